// Round 9
// baseline (28.018 us; speedup 1.0000x reference)
//
#include <hip/hip_runtime.h>
#include <stdint.h>

// Forward kinematics, 24-joint chain. Round-9: 8 lanes/sample (3 joints each)
// + 3-round Kogge-Stone transform scan in 8-lane groups.
// Rationale (r6/r7/r8 all 26.6-28.0us): concurrency-capped at 8-16 waves/CU.
// This config: 4.6KB LDS/wave, 128-thr barrier-free blocks, bounds (128,6)
// -> 24 waves/CU (1.5x r6), shorter per-lane serial chain (~180 vs 390 VALU).
// Single-buffered: rely on wave TLP, not intra-wave pipelining (r8 disproved).
// Roofline: 75.5MB in + 37.7MB out ~= 18us @ 6.3TB/s.

#define N_JOINTS 24

#define GLOAD_LDS16(gptr, lptr)                                            \
  __builtin_amdgcn_global_load_lds(                                        \
      (const __attribute__((address_space(1))) uint32_t*)(gptr),           \
      (__attribute__((address_space(3))) uint32_t*)(lptr), 16, 0, 0)

__global__ __launch_bounds__(128, 6) void fk_kernel(
    const float4* __restrict__ ain,   // angles as float4: [N*36]
    const float*  __restrict__ xyz,   // [24][3]
    float4* __restrict__ aout)        // out as float4: [N*18]
{
    // per-wave region: 8 samples * 36 float4 = 288 float4 (4608 B), linear
    __shared__ float4 s_buf[2][288];
    __shared__ float  s_t[2][N_JOINTS * 3];

    const int tid  = threadIdx.x;
    const int w    = tid >> 6;        // wave 0/1 (fully independent)
    const int lane = tid & 63;
    const int s    = lane >> 3;       // local sample 0..7
    const int seg  = lane & 7;        // joints [seg*3, seg*3+3)

    // ---- per-wave local translations (joint 0 uses xyz0[0] raw) ----
    if (lane < N_JOINTS) {
        float x = xyz[lane * 3 + 0];
        float y = xyz[lane * 3 + 1];
        float z = xyz[lane * 3 + 2];
        if (lane > 0) {
            x -= xyz[lane * 3 - 3];
            y -= xyz[lane * 3 - 2];
            z -= xyz[lane * 3 - 1];
        }
        s_t[w][lane * 3 + 0] = x;
        s_t[w][lane * 3 + 1] = y;
        s_t[w][lane * 3 + 2] = z;
    }

    // ---- wave-local input stage: 288 float4 (4 full + 1 half instr) ----
    const size_t gb = (size_t)blockIdx.x * 576 + (size_t)(w * 288 + lane);
    GLOAD_LDS16(ain + gb +   0, &s_buf[w][  0]);
    GLOAD_LDS16(ain + gb +  64, &s_buf[w][ 64]);
    GLOAD_LDS16(ain + gb + 128, &s_buf[w][128]);
    GLOAD_LDS16(ain + gb + 192, &s_buf[w][192]);
    if (lane < 32)
        GLOAD_LDS16(ain + gb + 256, &s_buf[w][256]);
    asm volatile("s_waitcnt vmcnt(0) lgkmcnt(0)" ::: "memory");
    __builtin_amdgcn_sched_barrier(0);

    // ---- read this lane's 3 joints: 18 floats = 9 float2 ----
    const float2* __restrict__ inb =
        reinterpret_cast<const float2*>(&s_buf[w][0]);
    float2 dv[9];
    #pragma unroll
    for (int k = 0; k < 9; ++k)
        dv[k] = inb[s * 72 + seg * 9 + k];
    float d[18];
    #pragma unroll
    for (int k = 0; k < 9; ++k) { d[2*k] = dv[k].x; d[2*k+1] = dv[k].y; }

    float R[9], t[3];   // segment-local cumulative transform
    float o[9];         // 3 segment-local translations

    #pragma unroll
    for (int jl = 0; jl < 3; ++jl) {
        const int j = seg * 3 + jl;     // global joint id
        const float a1x = d[jl*6+0], a1y = d[jl*6+1], a1z = d[jl*6+2];
        const float a2x = d[jl*6+3], a2y = d[jl*6+4], a2z = d[jl*6+5];

        // Gram-Schmidt (Zhou 6D -> rows b1,b2,b3)
        const float inv1 = rsqrtf(a1x*a1x + a1y*a1y + a1z*a1z);
        const float b1x = a1x*inv1, b1y = a1y*inv1, b1z = a1z*inv1;
        const float dd = b1x*a2x + b1y*a2y + b1z*a2z;
        float b2x = a2x - dd*b1x, b2y = a2y - dd*b1y, b2z = a2z - dd*b1z;
        const float inv2 = rsqrtf(b2x*b2x + b2y*b2y + b2z*b2z);
        b2x *= inv2; b2y *= inv2; b2z *= inv2;
        const float b3x = b1y*b2z - b1z*b2y;
        const float b3y = b1z*b2x - b1x*b2z;
        const float b3z = b1x*b2y - b1y*b2x;
        const float Rj[9] = { b1x,b1y,b1z, b2x,b2y,b2z, b3x,b3y,b3z };

        const float tx = s_t[w][j*3+0], ty = s_t[w][j*3+1], tz = s_t[w][j*3+2];
        const float tlx = Rj[0]*tx + Rj[1]*ty + Rj[2]*tz;
        const float tly = Rj[3]*tx + Rj[4]*ty + Rj[5]*tz;
        const float tlz = Rj[6]*tx + Rj[7]*ty + Rj[8]*tz;

        if (jl == 0) {
            #pragma unroll
            for (int k = 0; k < 9; ++k) R[k] = Rj[k];
            t[0] = tlx; t[1] = tly; t[2] = tlz;
        } else {
            t[0] += R[0]*tlx + R[1]*tly + R[2]*tlz;
            t[1] += R[3]*tlx + R[4]*tly + R[5]*tlz;
            t[2] += R[6]*tlx + R[7]*tly + R[8]*tlz;
            float Nn[9];
            #pragma unroll
            for (int r2 = 0; r2 < 3; ++r2)
                #pragma unroll
                for (int c = 0; c < 3; ++c)
                    Nn[r2*3+c] = R[r2*3+0]*Rj[0*3+c]
                               + R[r2*3+1]*Rj[1*3+c]
                               + R[r2*3+2]*Rj[2*3+c];
            #pragma unroll
            for (int k = 0; k < 9; ++k) R[k] = Nn[k];
        }
        o[jl*3+0] = t[0];
        o[jl*3+1] = t[1];
        o[jl*3+2] = t[2];
    }

    // ---- Kogge-Stone inclusive scan over the 8 lanes of a sample ----
    // compose(L, X) = (L.R @ X.R, L.t + L.R @ X.t); width=8 subgroups.
    #pragma unroll
    for (int dd2 = 1; dd2 <= 4; dd2 *= 2) {
        float LR[9], Lt[3];
        #pragma unroll
        for (int k = 0; k < 9; ++k) LR[k] = __shfl_up(R[k], (unsigned)dd2, 8);
        #pragma unroll
        for (int c = 0; c < 3; ++c) Lt[c] = __shfl_up(t[c], (unsigned)dd2, 8);
        if (seg >= dd2) {
            float nt0 = Lt[0] + LR[0]*t[0] + LR[1]*t[1] + LR[2]*t[2];
            float nt1 = Lt[1] + LR[3]*t[0] + LR[4]*t[1] + LR[5]*t[2];
            float nt2 = Lt[2] + LR[6]*t[0] + LR[7]*t[1] + LR[8]*t[2];
            float Nn[9];
            #pragma unroll
            for (int r2 = 0; r2 < 3; ++r2)
                #pragma unroll
                for (int c = 0; c < 3; ++c)
                    Nn[r2*3+c] = LR[r2*3+0]*R[0*3+c]
                               + LR[r2*3+1]*R[1*3+c]
                               + LR[r2*3+2]*R[2*3+c];
            #pragma unroll
            for (int k = 0; k < 9; ++k) R[k] = Nn[k];
            t[0] = nt0; t[1] = nt1; t[2] = nt2;
        }
    }

    // Exclusive prefix = inclusive of lane-1 within the 8-group
    // (identity for seg 0; own-value garbage there fully overwritten).
    float ER[9], Et[3];
    #pragma unroll
    for (int k = 0; k < 9; ++k) ER[k] = __shfl_up(R[k], 1u, 8);
    #pragma unroll
    for (int c = 0; c < 3; ++c) Et[c] = __shfl_up(t[c], 1u, 8);
    if (seg == 0) {
        ER[0]=1.f; ER[1]=0.f; ER[2]=0.f;
        ER[3]=0.f; ER[4]=1.f; ER[5]=0.f;
        ER[6]=0.f; ER[7]=0.f; ER[8]=1.f;
        Et[0]=0.f; Et[1]=0.f; Et[2]=0.f;
    }

    // Fixup: global translation = Et + ER @ local.
    #pragma unroll
    for (int k = 0; k < 3; ++k) {
        const float ox = o[3*k+0], oy = o[3*k+1], oz = o[3*k+2];
        o[3*k+0] = Et[0] + ER[0]*ox + ER[1]*oy + ER[2]*oz;
        o[3*k+1] = Et[1] + ER[3]*ox + ER[4]*oy + ER[5]*oz;
        o[3*k+2] = Et[2] + ER[6]*ox + ER[7]*oy + ER[8]*oz;
    }

    // ---- out-stage into front of the wave's OWN region (input reads done:
    // in-order DS per wave, lockstep lanes) ----
    float* obf = reinterpret_cast<float*>(&s_buf[w][0]);
    #pragma unroll
    for (int i = 0; i < 9; ++i)
        obf[s * 72 + seg * 9 + i] = o[i];   // banks ~2/32 lanes each: free

    // ---- wave-local coalesced store: 8 samples * 18 = 144 float4 ----
    const size_t ob4 = (size_t)blockIdx.x * 288 + (size_t)(w * 144);
    aout[ob4 + lane]      = s_buf[w][lane];
    aout[ob4 + 64 + lane] = s_buf[w][64 + lane];
    if (lane < 16)
        aout[ob4 + 128 + lane] = s_buf[w][128 + lane];
}

extern "C" void kernel_launch(void* const* d_in, const int* in_sizes, int n_in,
                              void* d_out, int out_size, void* d_ws, size_t ws_size,
                              hipStream_t stream) {
    const float* angles = (const float*)d_in[0];   // [N][24][6] f32
    const float* xyz    = (const float*)d_in[1];   // [1][24][3] f32
    float* out = (float*)d_out;

    const int N = in_sizes[0] / (N_JOINTS * 6);    // 131072 = 8192 * 16
    const int grid = N / 16;                        // 16 samples per block
    fk_kernel<<<grid, 128, 0, stream>>>(
        reinterpret_cast<const float4*>(angles), xyz,
        reinterpret_cast<float4*>(out));
}

// Round 10
// 25.131 us; speedup vs baseline: 1.1149x; 1.1149x over previous
//
#include <hip/hip_runtime.h>
#include <stdint.h>

// Forward kinematics, 24-joint chain, 4 lanes/sample + Kogge-Stone scan.
// Round-10: EXACT round-6 structure (best measured: 26.6us) with ONE change:
// nontemporal (nt) loads/stores on all global streaming traffic.
// r6-r9 showed dur is invariant (26.6-28.0) to occupancy/pipelining/structure
// -> suspect cache-path throttling of the zero-reuse 113MB stream.
// Roofline: 75.5MB in + 37.7MB out ~= 18us @ 6.3TB/s.

#define N_JOINTS 24
#define SAMPLES_PER_BLOCK 32
#define BLOCK_THREADS 128

typedef float v4f __attribute__((ext_vector_type(4)));
typedef float v2f __attribute__((ext_vector_type(2)));

__global__ __launch_bounds__(BLOCK_THREADS, 4) void fk_kernel(
    const v4f* __restrict__ ain,   // angles as float4: [N*36]
    const float* __restrict__ xyz, // [24][3]
    v4f* __restrict__ aout)        // out as float4: [N*18]
{
    // 32 samples * 37 float4 (36 data + 1 pad) = 18944 B; reused for output.
    __shared__ v4f  s_buf[SAMPLES_PER_BLOCK * 37];
    __shared__ float s_t[N_JOINTS * 3];

    const int tid = threadIdx.x;

    // Per-joint local translations (joint 0 uses xyz0[0] raw).
    if (tid < N_JOINTS) {
        float x = xyz[tid * 3 + 0];
        float y = xyz[tid * 3 + 1];
        float z = xyz[tid * 3 + 2];
        if (tid > 0) {
            x -= xyz[(tid - 1) * 3 + 0];
            y -= xyz[(tid - 1) * 3 + 1];
            z -= xyz[(tid - 1) * 3 + 2];
        }
        s_t[tid * 3 + 0] = x; s_t[tid * 3 + 1] = y; s_t[tid * 3 + 2] = z;
    }

    // ---- Coalesced nt input stage: 32 samples * 36 float4 = 1152 float4 ----
    const size_t in_base = (size_t)blockIdx.x * (SAMPLES_PER_BLOCK * 36);
    #pragma unroll
    for (int it = 0; it < 9; ++it) {
        const int g = tid + BLOCK_THREADS * it;   // 0..1151, lane-linear
        const int s = g / 36;                     // compiler magic-div
        const int r = g - s * 36;
        s_buf[s * 37 + r] = __builtin_nontemporal_load(&ain[in_base + g]);
    }
    __syncthreads();

    // ---- Compute: lane group of 4 per sample ----
    const int s   = tid >> 2;    // local sample 0..31
    const int seg = tid & 3;     // chain segment: joints [seg*6, seg*6+6)
    const v4f* __restrict__ row = &s_buf[s * 37 + seg * 9];

    float R[9], t[3];    // segment-local cumulative transform
    float o[18];         // 6 segment-local translations

    #pragma unroll
    for (int p = 0; p < 3; ++p) {           // 2 joints per float4-triple
        const v4f v0 = row[p * 3 + 0];
        const v4f v1 = row[p * 3 + 1];
        const v4f v2 = row[p * 3 + 2];
        float d6[12];
        d6[0] = v0.x; d6[1] = v0.y; d6[2]  = v0.z; d6[3]  = v0.w;
        d6[4] = v1.x; d6[5] = v1.y; d6[6]  = v1.z; d6[7]  = v1.w;
        d6[8] = v2.x; d6[9] = v2.y; d6[10] = v2.z; d6[11] = v2.w;

        #pragma unroll
        for (int h = 0; h < 2; ++h) {
            const int jl = p * 2 + h;       // 0..5 within segment
            const int j  = seg * 6 + jl;    // global joint id
            const float a1x = d6[h * 6 + 0], a1y = d6[h * 6 + 1], a1z = d6[h * 6 + 2];
            const float a2x = d6[h * 6 + 3], a2y = d6[h * 6 + 4], a2z = d6[h * 6 + 5];

            // Gram-Schmidt (Zhou 6D -> rows b1,b2,b3); rsqrtf -> v_rsq_f32
            const float inv1 = rsqrtf(a1x * a1x + a1y * a1y + a1z * a1z);
            const float b1x = a1x * inv1, b1y = a1y * inv1, b1z = a1z * inv1;
            const float dd = b1x * a2x + b1y * a2y + b1z * a2z;
            float b2x = a2x - dd * b1x, b2y = a2y - dd * b1y, b2z = a2z - dd * b1z;
            const float inv2 = rsqrtf(b2x * b2x + b2y * b2y + b2z * b2z);
            b2x *= inv2; b2y *= inv2; b2z *= inv2;
            const float b3x = b1y * b2z - b1z * b2y;
            const float b3y = b1z * b2x - b1x * b2z;
            const float b3z = b1x * b2y - b1y * b2x;
            const float Rj[9] = { b1x, b1y, b1z,  b2x, b2y, b2z,  b3x, b3y, b3z };

            const float tx = s_t[j * 3 + 0], ty = s_t[j * 3 + 1], tz = s_t[j * 3 + 2];
            const float tlx = Rj[0] * tx + Rj[1] * ty + Rj[2] * tz;
            const float tly = Rj[3] * tx + Rj[4] * ty + Rj[5] * tz;
            const float tlz = Rj[6] * tx + Rj[7] * ty + Rj[8] * tz;

            if (jl == 0) {
                #pragma unroll
                for (int k = 0; k < 9; ++k) R[k] = Rj[k];
                t[0] = tlx; t[1] = tly; t[2] = tlz;
            } else {
                t[0] += R[0] * tlx + R[1] * tly + R[2] * tlz;
                t[1] += R[3] * tlx + R[4] * tly + R[5] * tlz;
                t[2] += R[6] * tlx + R[7] * tly + R[8] * tlz;
                float Nn[9];
                #pragma unroll
                for (int r2 = 0; r2 < 3; ++r2)
                    #pragma unroll
                    for (int c = 0; c < 3; ++c)
                        Nn[r2 * 3 + c] = R[r2 * 3 + 0] * Rj[0 * 3 + c]
                                       + R[r2 * 3 + 1] * Rj[1 * 3 + c]
                                       + R[r2 * 3 + 2] * Rj[2 * 3 + c];
                #pragma unroll
                for (int k = 0; k < 9; ++k) R[k] = Nn[k];
            }
            o[jl * 3 + 0] = t[0];
            o[jl * 3 + 1] = t[1];
            o[jl * 3 + 2] = t[2];
        }
    }

    // ---- Kogge-Stone inclusive scan of (R,t) over the 4 lanes of a sample.
    // compose(L, X) = (L.R @ X.R, L.t + L.R @ X.t); predicated on seg >= d.
    #pragma unroll
    for (int d = 1; d <= 2; d *= 2) {
        float LR[9], Lt[3];
        #pragma unroll
        for (int k = 0; k < 9; ++k) LR[k] = __shfl_up(R[k], (unsigned)d);
        #pragma unroll
        for (int c = 0; c < 3; ++c) Lt[c] = __shfl_up(t[c], (unsigned)d);
        if (seg >= d) {
            float nt0 = Lt[0] + LR[0] * t[0] + LR[1] * t[1] + LR[2] * t[2];
            float nt1 = Lt[1] + LR[3] * t[0] + LR[4] * t[1] + LR[5] * t[2];
            float nt2 = Lt[2] + LR[6] * t[0] + LR[7] * t[1] + LR[8] * t[2];
            float Nn[9];
            #pragma unroll
            for (int r2 = 0; r2 < 3; ++r2)
                #pragma unroll
                for (int c = 0; c < 3; ++c)
                    Nn[r2 * 3 + c] = LR[r2 * 3 + 0] * R[0 * 3 + c]
                                   + LR[r2 * 3 + 1] * R[1 * 3 + c]
                                   + LR[r2 * 3 + 2] * R[2 * 3 + c];
            #pragma unroll
            for (int k = 0; k < 9; ++k) R[k] = Nn[k];
            t[0] = nt0; t[1] = nt1; t[2] = nt2;
        }
    }

    // Exclusive prefix = inclusive of lane-1 (identity for seg 0; the
    // cross-sample garbage pulled at seg==0 is fully overwritten).
    float ER[9], Et[3];
    #pragma unroll
    for (int k = 0; k < 9; ++k) ER[k] = __shfl_up(R[k], 1u);
    #pragma unroll
    for (int c = 0; c < 3; ++c) Et[c] = __shfl_up(t[c], 1u);
    if (seg == 0) {
        ER[0] = 1.f; ER[1] = 0.f; ER[2] = 0.f;
        ER[3] = 0.f; ER[4] = 1.f; ER[5] = 0.f;
        ER[6] = 0.f; ER[7] = 0.f; ER[8] = 1.f;
        Et[0] = 0.f; Et[1] = 0.f; Et[2] = 0.f;
    }

    // Fixup: global translation = Et + ER @ local.
    #pragma unroll
    for (int k = 0; k < 6; ++k) {
        const float ox = o[3 * k + 0], oy = o[3 * k + 1], oz = o[3 * k + 2];
        o[3 * k + 0] = Et[0] + ER[0] * ox + ER[1] * oy + ER[2] * oz;
        o[3 * k + 1] = Et[1] + ER[3] * ox + ER[4] * oy + ER[5] * oz;
        o[3 * k + 2] = Et[2] + ER[6] * ox + ER[7] * oy + ER[8] * oz;
    }

    // ---- Stage output to LDS (linear layout), then coalesced nt store ----
    __syncthreads();   // all LDS input reads done; safe to overwrite s_buf
    v2f* ob = reinterpret_cast<v2f*>(s_buf);
    #pragma unroll
    for (int q = 0; q < 9; ++q) {         // thread's 18 floats at float idx tid*18
        v2f v; v.x = o[2 * q + 0]; v.y = o[2 * q + 1];
        ob[tid * 9 + q] = v;              // odd float2 stride => conflict-light
    }
    __syncthreads();

    // 32 samples * 18 float4 = 576 float4; 128 threads -> 4.5 iterations.
    const size_t out_base = (size_t)blockIdx.x * (SAMPLES_PER_BLOCK * 18);
    #pragma unroll
    for (int it = 0; it < 4; ++it)
        __builtin_nontemporal_store(s_buf[tid + BLOCK_THREADS * it],
                                    &aout[out_base + tid + BLOCK_THREADS * it]);
    if (tid < 64)
        __builtin_nontemporal_store(s_buf[512 + tid],
                                    &aout[out_base + 512 + tid]);
}

extern "C" void kernel_launch(void* const* d_in, const int* in_sizes, int n_in,
                              void* d_out, int out_size, void* d_ws, size_t ws_size,
                              hipStream_t stream) {
    const float* angles = (const float*)d_in[0];   // [N][24][6] f32
    const float* xyz    = (const float*)d_in[1];   // [1][24][3] f32
    float* out = (float*)d_out;

    const int N = in_sizes[0] / (N_JOINTS * 6);    // 131072; divisible by 32
    const int grid = N / SAMPLES_PER_BLOCK;        // 4096 blocks
    fk_kernel<<<grid, BLOCK_THREADS, 0, stream>>>(
        reinterpret_cast<const v4f*>(angles), xyz,
        reinterpret_cast<v4f*>(out));
}